// Round 1
// baseline (570.877 us; speedup 1.0000x reference)
//
#include <hip/hip_runtime.h>
#include <cstdint>
#include <cstddef>

// Problem dims (fixed by setup_inputs)
#define B_N 8
#define Q_N 1024
#define K_N 4096
#define H_N 512
#define C_N 1024        // 2H
#define R_N (B_N * Q_N) // 8192 rows total

// MFMA fragment/acc types (guide §3: short8 = 8 bf16 = 4 VGPRs)
typedef short bf16x8 __attribute__((ext_vector_type(8)));
typedef float f32x4 __attribute__((ext_vector_type(4)));

// address-space helper types for global_load_lds
typedef const void __attribute__((address_space(1))) gas_void;
typedef void __attribute__((address_space(3))) las_void;

__device__ __forceinline__ unsigned short f2bf(float f) {
    union { float f; unsigned u; } v; v.f = f;
    unsigned u = v.u;
    u += 0x7FFFu + ((u >> 16) & 1u);   // RNE
    return (unsigned short)(u >> 16);
}
__device__ __forceinline__ float bf2f(unsigned short h) {
    union { unsigned u; float f; } v; v.u = ((unsigned)h) << 16;
    return v.f;
}

__device__ __forceinline__ f32x4 mfma16(bf16x8 a, bf16x8 b, f32x4 c) {
    return __builtin_amdgcn_mfma_f32_16x16x32_bf16(a, b, c, 0, 0, 0);
}

// ---------------- K0a: fp32 -> bf16 hi/lo split (4 elems/thread) ----------------
__global__ void k_split(const float* __restrict__ x, unsigned short* __restrict__ hi,
                        unsigned short* __restrict__ lo, int n4) {
    int i = blockIdx.x * 256 + threadIdx.x;
    if (i >= n4) return;
    float4 v = reinterpret_cast<const float4*>(x)[i];
    ushort4 h, l;
    h.x = f2bf(v.x); l.x = f2bf(v.x - bf2f(h.x));
    h.y = f2bf(v.y); l.y = f2bf(v.y - bf2f(h.y));
    h.z = f2bf(v.z); l.z = f2bf(v.z - bf2f(h.z));
    h.w = f2bf(v.w); l.w = f2bf(v.w - bf2f(h.w));
    reinterpret_cast<ushort4*>(hi)[i] = h;
    reinterpret_cast<ushort4*>(lo)[i] = l;
}

__global__ void k_cvt(const float* __restrict__ x, unsigned short* __restrict__ hi, int n4) {
    int i = blockIdx.x * 256 + threadIdx.x;
    if (i >= n4) return;
    float4 v = reinterpret_cast<const float4*>(x)[i];
    ushort4 h;
    h.x = f2bf(v.x); h.y = f2bf(v.y); h.z = f2bf(v.z); h.w = f2bf(v.w);
    reinterpret_cast<ushort4*>(hi)[i] = h;
}

// ---------------- K0b: transpose ctx_hi [B][K][H] -> [B][H][K] (bf16) ----------------
__global__ void k_transpose(const unsigned short* __restrict__ src, unsigned short* __restrict__ dst) {
    __shared__ unsigned short tile[32][33];
    const int b = blockIdx.z;
    const int k0 = blockIdx.x * 32;
    const int h0 = blockIdx.y * 32;
    const unsigned short* s = src + (size_t)b * K_N * H_N;
    unsigned short* d = dst + (size_t)b * H_N * K_N;
    const int tx = threadIdx.x & 31;
    const int ty = threadIdx.x >> 5; // 0..7
#pragma unroll
    for (int r = 0; r < 32; r += 8)
        tile[ty + r][tx] = s[(size_t)(k0 + ty + r) * H_N + (h0 + tx)];
    __syncthreads();
#pragma unroll
    for (int r = 0; r < 32; r += 8)
        d[(size_t)(h0 + ty + r) * K_N + (k0 + tx)] = tile[tx][ty + r];
}

// ---------------- async stage: 128x32 bf16 tile, global -> LDS, 16B/lane ----------------
// LDS layout row-major [128][32] shorts, exactly in lane order (no padding: global_load_lds
// dest is wave-uniform base + lane*16 — m104/m108).
__device__ __forceinline__ void stage_tile(const unsigned short* __restrict__ g, int ld,
                                           unsigned short* __restrict__ lds) {
    const int t = threadIdx.x;
    const int wbase = t & ~63;
#pragma unroll
    for (int i = 0; i < 2; i++) {
        int idx = i * 256 + t;                       // 0..511 lane-loads
        const unsigned short* ga = g + (size_t)(idx >> 2) * ld + (idx & 3) * 8;
        unsigned short* la = lds + (size_t)(i * 256 + wbase) * 8; // wave-uniform base
        __builtin_amdgcn_global_load_lds((gas_void*)ga, (las_void*)la, 16, 0, 0);
    }
}

// ---------------- K1: S = output . context^T  (bf16x3 split, fp32-accurate) ----------------
// grid (K/128, Q/128, B), 256 threads = 4 waves, each wave a 64x64 quadrant.
__global__ __launch_bounds__(256, 2)
void k_scores(const unsigned short* __restrict__ outHi, const unsigned short* __restrict__ outLo,
              const unsigned short* __restrict__ ctxHi, const unsigned short* __restrict__ ctxLo,
              float* __restrict__ S) {
    __shared__ unsigned short Ah[128 * 32], Al[128 * 32], Bh[128 * 32], Bl[128 * 32];
    const int b = blockIdx.z;
    const int q0 = blockIdx.y * 128;
    const int k0 = blockIdx.x * 128;
    const unsigned short* Ahg = outHi + ((size_t)b * Q_N + q0) * H_N;
    const unsigned short* Alg = outLo + ((size_t)b * Q_N + q0) * H_N;
    const unsigned short* Bhg = ctxHi + ((size_t)b * K_N + k0) * H_N;
    const unsigned short* Blg = ctxLo + ((size_t)b * K_N + k0) * H_N;
    const int lane = threadIdx.x & 63;
    const int w = threadIdx.x >> 6;
    const int wr = (w >> 1) * 64;
    const int wc = (w & 1) * 64;
    const int fm = lane & 15;         // fragment row within 16-tile
    const int fg = (lane >> 4) * 8;   // k-octet offset

    f32x4 acc[4][4];
#pragma unroll
    for (int i = 0; i < 4; i++)
#pragma unroll
        for (int j = 0; j < 4; j++) acc[i][j] = (f32x4){0.f, 0.f, 0.f, 0.f};

    for (int kc = 0; kc < H_N; kc += 32) {
        stage_tile(Ahg + kc, H_N, Ah);
        stage_tile(Alg + kc, H_N, Al);
        stage_tile(Bhg + kc, H_N, Bh);
        stage_tile(Blg + kc, H_N, Bl);
        __syncthreads();
        bf16x8 ah[4], al[4], bh[4], bl[4];
#pragma unroll
        for (int i = 0; i < 4; i++) {
            ah[i] = *(const bf16x8*)&Ah[(wr + i * 16 + fm) * 32 + fg];
            al[i] = *(const bf16x8*)&Al[(wr + i * 16 + fm) * 32 + fg];
            bh[i] = *(const bf16x8*)&Bh[(wc + i * 16 + fm) * 32 + fg];
            bl[i] = *(const bf16x8*)&Bl[(wc + i * 16 + fm) * 32 + fg];
        }
#pragma unroll
        for (int i = 0; i < 4; i++)
#pragma unroll
            for (int j = 0; j < 4; j++) {
                acc[i][j] = mfma16(ah[i], bh[j], acc[i][j]);
                acc[i][j] = mfma16(ah[i], bl[j], acc[i][j]);
                acc[i][j] = mfma16(al[i], bh[j], acc[i][j]);
            }
        __syncthreads();
    }
    // epilogue: C/D layout col=lane&15, row=(lane>>4)*4+reg
    float* Sb = S + (size_t)b * Q_N * K_N;
    const int orow = (lane >> 4) * 4;
    const int ocol = lane & 15;
#pragma unroll
    for (int i = 0; i < 4; i++)
#pragma unroll
        for (int r = 0; r < 4; r++) {
            int q = q0 + wr + i * 16 + orow + r;
            float* dst = Sb + (size_t)q * K_N + (k0 + wc + ocol);
#pragma unroll
            for (int j = 0; j < 4; j++) dst[j * 16] = acc[i][j][r];
        }
}

// ---------------- K2: masked row softmax, in-place; also write bf16 P ----------------
__global__ __launch_bounds__(256)
void k_softmax(float* __restrict__ S, const int* __restrict__ mask, unsigned short* __restrict__ pbf) {
    const size_t r = blockIdx.x;
    float* row = S + r * K_N;
    const int* mrow = mask + r * K_N;
    unsigned short* prow = pbf + r * K_N;
    const int t = threadIdx.x;

    float4 v[4];
    float lmax = -1e30f;
#pragma unroll
    for (int i = 0; i < 4; i++) {
        int idx = i * 256 + t;
        float4 s = reinterpret_cast<const float4*>(row)[idx];
        int4 mk = reinterpret_cast<const int4*>(mrow)[idx];
        s.x = mk.x ? -1e30f : s.x;
        s.y = mk.y ? -1e30f : s.y;
        s.z = mk.z ? -1e30f : s.z;
        s.w = mk.w ? -1e30f : s.w;
        v[i] = s;
        lmax = fmaxf(fmaxf(fmaxf(lmax, s.x), fmaxf(s.y, s.z)), s.w);
    }
#pragma unroll
    for (int off = 32; off >= 1; off >>= 1)
        lmax = fmaxf(lmax, __shfl_xor(lmax, off, 64));
    __shared__ float redm[4];
    __shared__ float reds[4];
    const int wv = t >> 6;
    if ((t & 63) == 0) redm[wv] = lmax;
    __syncthreads();
    const float m = fmaxf(fmaxf(redm[0], redm[1]), fmaxf(redm[2], redm[3]));

    float4 e[4];
    float lsum = 0.f;
#pragma unroll
    for (int i = 0; i < 4; i++) {
        e[i].x = __expf(v[i].x - m);
        e[i].y = __expf(v[i].y - m);
        e[i].z = __expf(v[i].z - m);
        e[i].w = __expf(v[i].w - m);
        lsum += (e[i].x + e[i].y) + (e[i].z + e[i].w);
    }
#pragma unroll
    for (int off = 32; off >= 1; off >>= 1)
        lsum += __shfl_xor(lsum, off, 64);
    if ((t & 63) == 0) reds[wv] = lsum;
    __syncthreads();
    const float inv = 1.0f / (reds[0] + reds[1] + reds[2] + reds[3]);

#pragma unroll
    for (int i = 0; i < 4; i++) {
        int idx = i * 256 + t;
        float4 p;
        p.x = e[i].x * inv; p.y = e[i].y * inv; p.z = e[i].z * inv; p.w = e[i].w * inv;
        reinterpret_cast<float4*>(row)[idx] = p;
        ushort4 pb;
        pb.x = f2bf(p.x); pb.y = f2bf(p.y); pb.z = f2bf(p.z); pb.w = f2bf(p.w);
        reinterpret_cast<ushort4*>(prow)[idx] = pb;
    }
}

// ---------------- K3: mix = P . ctxT^T  (plain bf16) ----------------
// grid (H/128, Q/128, B)
__global__ __launch_bounds__(256, 2)
void k_mix(const unsigned short* __restrict__ P, const unsigned short* __restrict__ ctxT,
           unsigned short* __restrict__ mixBf) {
    __shared__ unsigned short At[128 * 32], Bt[128 * 32];
    const int b = blockIdx.z;
    const int q0 = blockIdx.y * 128;
    const int h0 = blockIdx.x * 128;
    const unsigned short* Ag = P + ((size_t)b * Q_N + q0) * K_N;
    const unsigned short* Bg = ctxT + ((size_t)b * H_N + h0) * K_N;
    const int lane = threadIdx.x & 63;
    const int w = threadIdx.x >> 6;
    const int wr = (w >> 1) * 64;
    const int wc = (w & 1) * 64;
    const int fm = lane & 15;
    const int fg = (lane >> 4) * 8;

    f32x4 acc[4][4];
#pragma unroll
    for (int i = 0; i < 4; i++)
#pragma unroll
        for (int j = 0; j < 4; j++) acc[i][j] = (f32x4){0.f, 0.f, 0.f, 0.f};

    for (int kc = 0; kc < K_N; kc += 32) {
        stage_tile(Ag + kc, K_N, At);
        stage_tile(Bg + kc, K_N, Bt);
        __syncthreads();
        bf16x8 a[4], bb[4];
#pragma unroll
        for (int i = 0; i < 4; i++) {
            a[i] = *(const bf16x8*)&At[(wr + i * 16 + fm) * 32 + fg];
            bb[i] = *(const bf16x8*)&Bt[(wc + i * 16 + fm) * 32 + fg];
        }
#pragma unroll
        for (int i = 0; i < 4; i++)
#pragma unroll
            for (int j = 0; j < 4; j++) acc[i][j] = mfma16(a[i], bb[j], acc[i][j]);
        __syncthreads();
    }
    const int orow = (lane >> 4) * 4;
    const int ocol = lane & 15;
#pragma unroll
    for (int i = 0; i < 4; i++)
#pragma unroll
        for (int r = 0; r < 4; r++) {
            int q = q0 + wr + i * 16 + orow + r;
            unsigned short* dst = mixBf + ((size_t)b * Q_N + q) * H_N + (h0 + wc + ocol);
#pragma unroll
            for (int j = 0; j < 4; j++) dst[j * 16] = f2bf(acc[i][j][r]);
        }
}

// ---------------- K4: out = tanh([mix | output] . W^T + b) ----------------
// grid (H/128, R/128). Reduction c in [0,1024): c<512 -> mixBf, else outHi.
__global__ __launch_bounds__(256, 2)
void k_outlin(const unsigned short* __restrict__ mixBf, const unsigned short* __restrict__ outHi,
              const unsigned short* __restrict__ Whi, const float* __restrict__ bias,
              float* __restrict__ out) {
    __shared__ unsigned short At[128 * 32], Bt[128 * 32];
    const int r0 = blockIdx.y * 128;
    const int h0 = blockIdx.x * 128;
    const int lane = threadIdx.x & 63;
    const int w = threadIdx.x >> 6;
    const int wr = (w >> 1) * 64;
    const int wc = (w & 1) * 64;
    const int fm = lane & 15;
    const int fg = (lane >> 4) * 8;

    f32x4 acc[4][4];
#pragma unroll
    for (int i = 0; i < 4; i++)
#pragma unroll
        for (int j = 0; j < 4; j++) acc[i][j] = (f32x4){0.f, 0.f, 0.f, 0.f};

    for (int kc = 0; kc < C_N; kc += 32) {
        const unsigned short* Ag = (kc < H_N)
            ? mixBf + (size_t)r0 * H_N + kc
            : outHi + (size_t)r0 * H_N + (kc - H_N);
        stage_tile(Ag, H_N, At);
        stage_tile(Whi + (size_t)h0 * C_N + kc, C_N, Bt);
        __syncthreads();
        bf16x8 a[4], bb[4];
#pragma unroll
        for (int i = 0; i < 4; i++) {
            a[i] = *(const bf16x8*)&At[(wr + i * 16 + fm) * 32 + fg];
            bb[i] = *(const bf16x8*)&Bt[(wc + i * 16 + fm) * 32 + fg];
        }
#pragma unroll
        for (int i = 0; i < 4; i++)
#pragma unroll
            for (int j = 0; j < 4; j++) acc[i][j] = mfma16(a[i], bb[j], acc[i][j]);
        __syncthreads();
    }
    const int orow = (lane >> 4) * 4;
    const int ocol = lane & 15;
#pragma unroll
    for (int i = 0; i < 4; i++)
#pragma unroll
        for (int r = 0; r < 4; r++) {
            int rr = r0 + wr + i * 16 + orow + r;
#pragma unroll
            for (int j = 0; j < 4; j++) {
                int h = h0 + wc + j * 16 + ocol;
                float v = acc[i][j][r] + bias[h];
                out[(size_t)rr * H_N + h] = tanhf(v);
            }
        }
}

extern "C" void kernel_launch(void* const* d_in, const int* in_sizes, int n_in,
                              void* d_out, int out_size, void* d_ws, size_t ws_size,
                              hipStream_t stream) {
    const float* d_output  = (const float*)d_in[0]; // [8,1024,512]
    const float* d_context = (const float*)d_in[1]; // [8,4096,512]
    const int*   d_mask    = (const int*)d_in[2];   // [8,1024,4096]
    const float* d_W       = (const float*)d_in[3]; // [512,1024]
    const float* d_bias    = (const float*)d_in[4]; // [512]

    float* out_res = (float*)d_out;                          // [8,1024,512]
    float* attn    = out_res + (size_t)R_N * H_N;            // [8,1024,4096]

    // workspace carve-up (~185 MiB total)
    char* ws = (char*)d_ws;
    unsigned short* ctxHi = (unsigned short*)ws; ws += (size_t)B_N * K_N * H_N * 2;
    unsigned short* ctxLo = (unsigned short*)ws; ws += (size_t)B_N * K_N * H_N * 2;
    unsigned short* ctxT  = (unsigned short*)ws; ws += (size_t)B_N * K_N * H_N * 2;
    unsigned short* outHi = (unsigned short*)ws; ws += (size_t)R_N * H_N * 2;
    unsigned short* outLo = (unsigned short*)ws; ws += (size_t)R_N * H_N * 2;
    unsigned short* Whi   = (unsigned short*)ws; ws += (size_t)H_N * C_N * 2;
    unsigned short* pBf   = (unsigned short*)ws; ws += (size_t)R_N * K_N * 2;
    unsigned short* mixBf = (unsigned short*)ws; ws += (size_t)R_N * H_N * 2;

    // K0: precision split / cvt / transpose
    k_split<<<dim3((R_N * H_N / 4) / 256), 256, 0, stream>>>(d_output, outHi, outLo, R_N * H_N / 4);
    k_split<<<dim3((B_N * K_N * H_N / 4) / 256), 256, 0, stream>>>(d_context, ctxHi, ctxLo,
                                                                   B_N * K_N * H_N / 4);
    k_cvt<<<dim3((H_N * C_N / 4) / 256), 256, 0, stream>>>(d_W, Whi, H_N * C_N / 4);
    k_transpose<<<dim3(K_N / 32, H_N / 32, B_N), 256, 0, stream>>>(ctxHi, ctxT);

    // K1: raw scores into attn region (mask applied in K2)
    k_scores<<<dim3(K_N / 128, Q_N / 128, B_N), 256, 0, stream>>>(outHi, outLo, ctxHi, ctxLo, attn);

    // K2: masked softmax in place, bf16 copy of P
    k_softmax<<<dim3(R_N), 256, 0, stream>>>(attn, d_mask, pBf);

    // K3: mix = P . context
    k_mix<<<dim3(H_N / 128, Q_N / 128, B_N), 256, 0, stream>>>(pBf, ctxT, mixBf);

    // K4: final linear + tanh
    k_outlin<<<dim3(H_N / 128, R_N / 128), 256, 0, stream>>>(mixBf, outHi, Whi, d_bias, out_res);
}